// Round 6
// baseline (98.642 us; speedup 1.0000x reference)
//
#include <hip/hip_runtime.h>
#include <cstdint>
#include <cstddef>

// Problem constants (match reference)
#define BB 64
#define QQ 900
#define DD 256
#define CC 91
#define MM 4500
#define MAXPREV 5

typedef float f4 __attribute__((ext_vector_type(4)));

// Output layout (flat float32, concatenated in reference return order)
constexpr size_t OUT_FN   = (size_t)BB * MM * DD;
constexpr size_t OUT_TID  = OUT_FN  + (size_t)BB * MM;
constexpr size_t OUT_MASK = OUT_TID + (size_t)BB * MM;
constexpr size_t OUT_NB   = OUT_MASK + (size_t)BB * MM;

// Workspace layout
constexpr size_t WS_MAP   = 0;                               // BB*MM ints
constexpr size_t WS_PFLAG = (size_t)BB * MM * sizeof(int);   // BB*QQ bytes

// One wave per (b,q): max over C logits, sigmoid, threshold -> flag byte.
__global__ void __launch_bounds__(256) pred_flag_kernel(
        const float* __restrict__ pred_classes,
        unsigned char* __restrict__ pflag) {
    int row  = blockIdx.x * 4 + (threadIdx.x >> 6);   // grid exact: BB*QQ/4
    int lane = threadIdx.x & 63;
    const float* p = pred_classes + (size_t)row * CC;
    float m = -3.0e38f;
    if (lane < CC)      m = __builtin_nontemporal_load(p + lane);
    if (lane + 64 < CC) m = fmaxf(m, __builtin_nontemporal_load(p + lane + 64));
    #pragma unroll
    for (int off = 32; off > 0; off >>= 1) m = fmaxf(m, __shfl_xor(m, off));
    if (lane == 0) {
        float s = 1.0f / (1.0f + expf(-m));   // matches jax.nn.sigmoid
        pflag[row] = (s >= 0.8f) ? 1 : 0;
    }
}

// One 1024-thread block per batch. Per-batch mask-format detect, 3 stable
// prefix-scan rounds; meta (fn/tid/mask) written DURING the scatter (dense,
// coalesced); tail [nb,MM) filled with -1/defaults so consumers need no nb.
// map[b][dest] = source code (< MM: mem row; >= MM: pred row code-MM; -1: zero).
__global__ void __launch_bounds__(1024) scan_kernel(
        const int* __restrict__ mem_fn, const int* __restrict__ mem_tid,
        const void* __restrict__ mem_mask, const unsigned char* __restrict__ pflag,
        const int* __restrict__ pred_ids, const int* __restrict__ cur_frames,
        int* __restrict__ map, float* __restrict__ out) {
    const int b = blockIdx.x;
    const int tid = threadIdx.x, lane = tid & 63, wid = tid >> 6;  // 16 waves
    const int cf = cur_frames[b];
    const int thr = cf - MAXPREV;
    int* mapb = map + (size_t)b * MM;
    float* ofn   = out + OUT_FN   + (size_t)b * MM;
    float* otid  = out + OUT_TID  + (size_t)b * MM;
    float* omask = out + OUT_MASK + (size_t)b * MM;
    __shared__ int wsum[16];
    __shared__ int sdet[16];

    // ---- format detect on this batch's byte window (global property):
    // int32 0/1 data has bytes at offset %4 != 0 all zero.
    {
        const uint32_t* w = (const uint32_t*)((const unsigned char*)mem_mask
                                              + (size_t)b * MM);
        uint32_t local = 0;
        #pragma unroll
        for (int i = tid; i < MM / 4; i += 1024) local |= w[i] & 0xFFFFFF00u;
        int found = (__ballot(local != 0) != 0ull) ? 1 : 0;
        if (lane == 0) sdet[wid] = found;
    }
    __syncthreads();
    int det = 0;
    #pragma unroll
    for (int w = 0; w < 16; w++) det |= sdet[w];
    const bool boolfmt = det != 0;   // 1 => byte-bool format
    const unsigned char* m8  = (const unsigned char*)mem_mask;
    const int*           m32 = (const int*)mem_mask;

    int base = 0;
    // ---- round A: mem rows 0..4095, 4 per thread (stable within thread) ----
    {
        int4 fn4 = ((const int4*)(mem_fn  + (size_t)b * MM))[tid];
        int4 td4 = ((const int4*)(mem_tid + (size_t)b * MM))[tid];
        uint32_t mk4;
        if (boolfmt) {
            mk4 = ((const uint32_t*)(m8 + (size_t)b * MM))[tid];
        } else {
            int4 m = ((const int4*)(m32 + (size_t)b * MM))[tid];
            mk4 = (m.x ? 0xFFu : 0) | (m.y ? 0xFF00u : 0) |
                  (m.z ? 0xFF0000u : 0) | (m.w ? 0xFF000000u : 0);
        }
        int f0 = (fn4.x > thr) && (mk4 & 0xFFu);
        int f1 = (fn4.y > thr) && (mk4 & 0xFF00u);
        int f2 = (fn4.z > thr) && (mk4 & 0xFF0000u);
        int f3 = (fn4.w > thr) && (mk4 & 0xFF000000u);
        int cnt = f0 + f1 + f2 + f3;
        int incl = cnt;
        #pragma unroll
        for (int off = 1; off < 64; off <<= 1) {
            int nv = __shfl_up(incl, off);
            if (lane >= off) incl += nv;
        }
        if (lane == 63) wsum[wid] = incl;
        __syncthreads();
        int woff = 0, total = 0;
        #pragma unroll
        for (int w = 0; w < 16; w++) { if (w < wid) woff += wsum[w]; total += wsum[w]; }
        int pos = woff + (incl - cnt);
        int r = 4 * tid;
        if (f0) { mapb[pos] = r;   ofn[pos] = (float)fn4.x; otid[pos] = (float)td4.x; omask[pos] = 1.0f; pos++; }
        if (f1) { mapb[pos] = r+1; ofn[pos] = (float)fn4.y; otid[pos] = (float)td4.y; omask[pos] = 1.0f; pos++; }
        if (f2) { mapb[pos] = r+2; ofn[pos] = (float)fn4.z; otid[pos] = (float)td4.z; omask[pos] = 1.0f; pos++; }
        if (f3) { mapb[pos] = r+3; ofn[pos] = (float)fn4.w; otid[pos] = (float)td4.w; omask[pos] = 1.0f; }
        base = total;
        __syncthreads();
    }
    // ---- round B: mem rows 4096..4499 ----
    {
        int i = 4096 + tid;
        int flag = 0, fn = 0, tv = 0;
        if (tid < MM - 4096) {
            fn = mem_fn[(size_t)b * MM + i];
            tv = mem_tid[(size_t)b * MM + i];
            int mk = boolfmt ? (m8[(size_t)b * MM + i] != 0)
                             : (m32[(size_t)b * MM + i] != 0);
            flag = (fn > thr) && mk;
        }
        int incl = flag;
        #pragma unroll
        for (int off = 1; off < 64; off <<= 1) {
            int nv = __shfl_up(incl, off);
            if (lane >= off) incl += nv;
        }
        if (lane == 63) wsum[wid] = incl;
        __syncthreads();
        int woff = 0, total = 0;
        #pragma unroll
        for (int w = 0; w < 16; w++) { if (w < wid) woff += wsum[w]; total += wsum[w]; }
        if (flag) {
            int pos = base + woff + incl - 1;
            mapb[pos] = i; ofn[pos] = (float)fn; otid[pos] = (float)tv; omask[pos] = 1.0f;
        }
        base += total;
        __syncthreads();
    }
    // ---- round C: preds (QQ=900 <= 1024, single round) ----
    {
        int flag = (tid < QQ) ? (int)pflag[(size_t)b * QQ + tid] : 0;
        int incl = flag;
        #pragma unroll
        for (int off = 1; off < 64; off <<= 1) {
            int nv = __shfl_up(incl, off);
            if (lane >= off) incl += nv;
        }
        if (lane == 63) wsum[wid] = incl;
        __syncthreads();
        int woff = 0, total = 0;
        #pragma unroll
        for (int w = 0; w < 16; w++) { if (w < wid) woff += wsum[w]; total += wsum[w]; }
        int dest = base + woff + incl - 1;
        if (flag && dest < MM) {
            mapb[dest] = MM + tid;
            ofn[dest]  = (float)cf;
            otid[dest] = (float)pred_ids[(size_t)b * QQ + tid];
            omask[dest] = 1.0f;
        }
        base += total;
    }
    int nb = base < MM ? base : MM;
    // ---- tail fill [nb, MM): disjoint from scatter region, no sync needed ----
    for (int d = nb + tid; d < MM; d += 1024) {
        mapb[d] = -1; ofn[d] = -1.0f; otid[d] = 0.0f; omask[d] = 0.0f;
    }
    if (tid == 0) out[OUT_NB + b] = (float)nb;
}

// One wave per output row: pure gather (64 lanes x float4) or zero-fill.
// NT loads (read-once gather); REGULAR stores (write-combining in L2,
// matches the ~6.9 TB/s the harness fill demonstrates with plain stores).
__global__ void __launch_bounds__(1024) emb_kernel(
        const float* __restrict__ mem_emb, const float* __restrict__ pred_emb,
        const int* __restrict__ map, float* __restrict__ out) {
    int row  = blockIdx.x * 16 + (threadIdx.x >> 6);   // grid exact: BB*MM/16
    int lane = threadIdx.x & 63;
    int b = row / MM;
    int code = map[row];

    f4 v = (f4)0.0f;
    if (code >= 0) {
        const float* src = (code < MM)
            ? (mem_emb  + ((size_t)b * MM + code) * DD)
            : (pred_emb + ((size_t)b * QQ + (code - MM)) * DD);
        v = __builtin_nontemporal_load((const f4*)src + lane);
    }
    ((f4*)(out + (size_t)row * DD))[lane] = v;
}

extern "C" void kernel_launch(void* const* d_in, const int* in_sizes, int n_in,
                              void* d_out, int out_size, void* d_ws, size_t ws_size,
                              hipStream_t stream) {
    const float* mem_emb    = (const float*)d_in[0];
    const int*   mem_fn     = (const int*)d_in[1];
    const int*   mem_tid    = (const int*)d_in[2];
    const void*  mem_mask   = d_in[3];
    const float* pred_emb   = (const float*)d_in[4];
    const float* pred_cls   = (const float*)d_in[5];
    const int*   pred_ids   = (const int*)d_in[6];
    const int*   cur_frames = (const int*)d_in[7];
    float* out = (float*)d_out;

    int* map             = (int*)((char*)d_ws + WS_MAP);
    unsigned char* pflag = (unsigned char*)d_ws + WS_PFLAG;

    pred_flag_kernel<<<(BB * QQ) / 4, 256, 0, stream>>>(pred_cls, pflag);
    scan_kernel<<<BB, 1024, 0, stream>>>(mem_fn, mem_tid, mem_mask, pflag,
                                         pred_ids, cur_frames, map, out);
    emb_kernel<<<(BB * MM) / 16, 1024, 0, stream>>>(mem_emb, pred_emb, map, out);
}

// Round 7
// 82.328 us; speedup vs baseline: 1.1982x; 1.1982x over previous
//
#include <hip/hip_runtime.h>
#include <cstdint>
#include <cstddef>

// Problem constants (match reference)
#define BB 64
#define QQ 900
#define DD 256
#define CC 91
#define MM 4500
#define MAXPREV 5

typedef float f4 __attribute__((ext_vector_type(4)));

// Output layout (flat float32, concatenated in reference return order)
constexpr size_t OUT_FN   = (size_t)BB * MM * DD;
constexpr size_t OUT_TID  = OUT_FN  + (size_t)BB * MM;
constexpr size_t OUT_MASK = OUT_TID + (size_t)BB * MM;
constexpr size_t OUT_NB   = OUT_MASK + (size_t)BB * MM;

// Workspace layout
constexpr size_t WS_MAP   = 0;                               // BB*MM ints
constexpr size_t WS_PFLAG = (size_t)BB * MM * sizeof(int);   // BB*QQ bytes

// One wave per (b,q): max over C logits, sigmoid, threshold -> flag byte.
__global__ void __launch_bounds__(256) pred_flag_kernel(
        const float* __restrict__ pred_classes,
        unsigned char* __restrict__ pflag) {
    int row  = blockIdx.x * 4 + (threadIdx.x >> 6);   // grid exact: BB*QQ/4
    int lane = threadIdx.x & 63;
    const float* p = pred_classes + (size_t)row * CC;
    float m = -3.0e38f;
    if (lane < CC)      m = __builtin_nontemporal_load(p + lane);
    if (lane + 64 < CC) m = fmaxf(m, __builtin_nontemporal_load(p + lane + 64));
    #pragma unroll
    for (int off = 32; off > 0; off >>= 1) m = fmaxf(m, __shfl_xor(m, off));
    if (lane == 0) {
        float s = 1.0f / (1.0f + expf(-m));   // matches jax.nn.sigmoid
        pflag[row] = (s >= 0.8f) ? 1 : 0;
    }
}

// One 1024-thread block per batch. Per-batch mask-format detect, 3 stable
// prefix-scan rounds; meta (fn/tid/mask) written DURING the scatter (dense,
// coalesced); tail [nb,MM) filled with -1/defaults so consumers need no nb.
// map[b][dest] = source code (< MM: mem row; >= MM: pred row code-MM; -1: zero).
__global__ void __launch_bounds__(1024) scan_kernel(
        const int* __restrict__ mem_fn, const int* __restrict__ mem_tid,
        const void* __restrict__ mem_mask, const unsigned char* __restrict__ pflag,
        const int* __restrict__ pred_ids, const int* __restrict__ cur_frames,
        int* __restrict__ map, float* __restrict__ out) {
    const int b = blockIdx.x;
    const int tid = threadIdx.x, lane = tid & 63, wid = tid >> 6;  // 16 waves
    const int cf = cur_frames[b];
    const int thr = cf - MAXPREV;
    int* mapb = map + (size_t)b * MM;
    float* ofn   = out + OUT_FN   + (size_t)b * MM;
    float* otid  = out + OUT_TID  + (size_t)b * MM;
    float* omask = out + OUT_MASK + (size_t)b * MM;
    __shared__ int wsum[16];
    __shared__ int sdet[16];

    // ---- format detect on this batch's byte window (global property):
    // int32 0/1 data has bytes at offset %4 != 0 all zero.
    {
        const uint32_t* w = (const uint32_t*)((const unsigned char*)mem_mask
                                              + (size_t)b * MM);
        uint32_t local = 0;
        #pragma unroll
        for (int i = tid; i < MM / 4; i += 1024) local |= w[i] & 0xFFFFFF00u;
        int found = (__ballot(local != 0) != 0ull) ? 1 : 0;
        if (lane == 0) sdet[wid] = found;
    }
    __syncthreads();
    int det = 0;
    #pragma unroll
    for (int w = 0; w < 16; w++) det |= sdet[w];
    const bool boolfmt = det != 0;   // 1 => byte-bool format
    const unsigned char* m8  = (const unsigned char*)mem_mask;
    const int*           m32 = (const int*)mem_mask;

    int base = 0;
    // ---- round A: mem rows 0..4095, 4 per thread (stable within thread) ----
    {
        int4 fn4 = ((const int4*)(mem_fn  + (size_t)b * MM))[tid];
        int4 td4 = ((const int4*)(mem_tid + (size_t)b * MM))[tid];
        uint32_t mk4;
        if (boolfmt) {
            mk4 = ((const uint32_t*)(m8 + (size_t)b * MM))[tid];
        } else {
            int4 m = ((const int4*)(m32 + (size_t)b * MM))[tid];
            mk4 = (m.x ? 0xFFu : 0) | (m.y ? 0xFF00u : 0) |
                  (m.z ? 0xFF0000u : 0) | (m.w ? 0xFF000000u : 0);
        }
        int f0 = (fn4.x > thr) && (mk4 & 0xFFu);
        int f1 = (fn4.y > thr) && (mk4 & 0xFF00u);
        int f2 = (fn4.z > thr) && (mk4 & 0xFF0000u);
        int f3 = (fn4.w > thr) && (mk4 & 0xFF000000u);
        int cnt = f0 + f1 + f2 + f3;
        int incl = cnt;
        #pragma unroll
        for (int off = 1; off < 64; off <<= 1) {
            int nv = __shfl_up(incl, off);
            if (lane >= off) incl += nv;
        }
        if (lane == 63) wsum[wid] = incl;
        __syncthreads();
        int woff = 0, total = 0;
        #pragma unroll
        for (int w = 0; w < 16; w++) { if (w < wid) woff += wsum[w]; total += wsum[w]; }
        int pos = woff + (incl - cnt);
        int r = 4 * tid;
        if (f0) { mapb[pos] = r;   ofn[pos] = (float)fn4.x; otid[pos] = (float)td4.x; omask[pos] = 1.0f; pos++; }
        if (f1) { mapb[pos] = r+1; ofn[pos] = (float)fn4.y; otid[pos] = (float)td4.y; omask[pos] = 1.0f; pos++; }
        if (f2) { mapb[pos] = r+2; ofn[pos] = (float)fn4.z; otid[pos] = (float)td4.z; omask[pos] = 1.0f; pos++; }
        if (f3) { mapb[pos] = r+3; ofn[pos] = (float)fn4.w; otid[pos] = (float)td4.w; omask[pos] = 1.0f; }
        base = total;
        __syncthreads();
    }
    // ---- round B: mem rows 4096..4499 ----
    {
        int i = 4096 + tid;
        int flag = 0, fn = 0, tv = 0;
        if (tid < MM - 4096) {
            fn = mem_fn[(size_t)b * MM + i];
            tv = mem_tid[(size_t)b * MM + i];
            int mk = boolfmt ? (m8[(size_t)b * MM + i] != 0)
                             : (m32[(size_t)b * MM + i] != 0);
            flag = (fn > thr) && mk;
        }
        int incl = flag;
        #pragma unroll
        for (int off = 1; off < 64; off <<= 1) {
            int nv = __shfl_up(incl, off);
            if (lane >= off) incl += nv;
        }
        if (lane == 63) wsum[wid] = incl;
        __syncthreads();
        int woff = 0, total = 0;
        #pragma unroll
        for (int w = 0; w < 16; w++) { if (w < wid) woff += wsum[w]; total += wsum[w]; }
        if (flag) {
            int pos = base + woff + incl - 1;
            mapb[pos] = i; ofn[pos] = (float)fn; otid[pos] = (float)tv; omask[pos] = 1.0f;
        }
        base += total;
        __syncthreads();
    }
    // ---- round C: preds (QQ=900 <= 1024, single round) ----
    {
        int flag = (tid < QQ) ? (int)pflag[(size_t)b * QQ + tid] : 0;
        int incl = flag;
        #pragma unroll
        for (int off = 1; off < 64; off <<= 1) {
            int nv = __shfl_up(incl, off);
            if (lane >= off) incl += nv;
        }
        if (lane == 63) wsum[wid] = incl;
        __syncthreads();
        int woff = 0, total = 0;
        #pragma unroll
        for (int w = 0; w < 16; w++) { if (w < wid) woff += wsum[w]; total += wsum[w]; }
        int dest = base + woff + incl - 1;
        if (flag && dest < MM) {
            mapb[dest] = MM + tid;
            ofn[dest]  = (float)cf;
            otid[dest] = (float)pred_ids[(size_t)b * QQ + tid];
            omask[dest] = 1.0f;
        }
        base += total;
    }
    int nb = base < MM ? base : MM;
    // ---- tail fill [nb, MM): disjoint from scatter region, no sync needed ----
    for (int d = nb + tid; d < MM; d += 1024) {
        mapb[d] = -1; ofn[d] = -1.0f; otid[d] = 0.0f; omask[d] = 0.0f;
    }
    if (tid == 0) out[OUT_NB + b] = (float)nb;
}

// One wave per output row: pure gather (64 lanes x float4) or zero-fill.
// REGULAR loads (let L2 stage the hole-y gather stream); NT stores
// (round-5/6 A/B: NT store > regular store here).
__global__ void __launch_bounds__(1024) emb_kernel(
        const float* __restrict__ mem_emb, const float* __restrict__ pred_emb,
        const int* __restrict__ map, float* __restrict__ out) {
    int row  = blockIdx.x * 16 + (threadIdx.x >> 6);   // grid exact: BB*MM/16
    int lane = threadIdx.x & 63;
    int b = row / MM;
    int code = map[row];

    f4 v = (f4)0.0f;
    if (code >= 0) {
        const float* src = (code < MM)
            ? (mem_emb  + ((size_t)b * MM + code) * DD)
            : (pred_emb + ((size_t)b * QQ + (code - MM)) * DD);
        v = ((const f4*)src)[lane];
    }
    __builtin_nontemporal_store(v, (f4*)(out + (size_t)row * DD) + lane);
}

extern "C" void kernel_launch(void* const* d_in, const int* in_sizes, int n_in,
                              void* d_out, int out_size, void* d_ws, size_t ws_size,
                              hipStream_t stream) {
    const float* mem_emb    = (const float*)d_in[0];
    const int*   mem_fn     = (const int*)d_in[1];
    const int*   mem_tid    = (const int*)d_in[2];
    const void*  mem_mask   = d_in[3];
    const float* pred_emb   = (const float*)d_in[4];
    const float* pred_cls   = (const float*)d_in[5];
    const int*   pred_ids   = (const int*)d_in[6];
    const int*   cur_frames = (const int*)d_in[7];
    float* out = (float*)d_out;

    int* map             = (int*)((char*)d_ws + WS_MAP);
    unsigned char* pflag = (unsigned char*)d_ws + WS_PFLAG;

    pred_flag_kernel<<<(BB * QQ) / 4, 256, 0, stream>>>(pred_cls, pflag);
    scan_kernel<<<BB, 1024, 0, stream>>>(mem_fn, mem_tid, mem_mask, pflag,
                                         pred_ids, cur_frames, map, out);
    emb_kernel<<<(BB * MM) / 16, 1024, 0, stream>>>(mem_emb, pred_emb, map, out);
}